// Round 1
// baseline (1662.200 us; speedup 1.0000x reference)
//
#include <hip/hip_runtime.h>
#include <cstdint>
#include <cmath>

// Problem constants (B=4, S=2048, H=2048, I=4096, E=8, K=2)
#define T_TOK 8192     // B*S
#define H_DIM 2048
#define I_DIM 4096
#define E_NUM 8
#define NROWS 16384    // T*K

typedef __bf16 bf16x8 __attribute__((ext_vector_type(8)));
typedef float f32x4 __attribute__((ext_vector_type(4)));

__device__ __forceinline__ uint16_t f2bf(float f) {
  union { float f; uint32_t u; } v; v.f = f;
  uint32_t u = v.u;
  uint32_t r = (u + 0x7fffu + ((u >> 16) & 1u)) >> 16;
  return (uint16_t)r;
}
__device__ __forceinline__ float bf2f(uint32_t b) {
  union { uint32_t u; float f; } v; v.u = b << 16;
  return v.f;
}

__device__ __forceinline__ float gelu_tanh(float x) {
  float u = 0.7978845608028654f * (x + 0.044715f * x * x * x);
  return 0.5f * x * (1.0f + tanhf(u));
}

// ---------------- router: logits -> softmax -> top-2, histogram ----------------
__global__ __launch_bounds__(256) void router_kernel(
    const float* __restrict__ x, const float* __restrict__ rw,
    int* __restrict__ expert_idx, float* __restrict__ expert_w,
    int* __restrict__ counts) {
  int t = blockIdx.x * 4 + (threadIdx.x >> 6);   // one wave per token
  int lane = threadIdx.x & 63;
  const float* xr = x + (size_t)t * H_DIM;
  float acc[E_NUM];
#pragma unroll
  for (int e = 0; e < E_NUM; ++e) acc[e] = 0.f;
  for (int j = 0; j < H_DIM / 64; ++j) {
    float xv = xr[lane + 64 * j];
#pragma unroll
    for (int e = 0; e < E_NUM; ++e) acc[e] += xv * rw[e * H_DIM + lane + 64 * j];
  }
#pragma unroll
  for (int e = 0; e < E_NUM; ++e) {
#pragma unroll
    for (int off = 32; off > 0; off >>= 1) acc[e] += __shfl_xor(acc[e], off);
  }
  if (lane == 0) {
    float mx = acc[0];
#pragma unroll
    for (int e = 1; e < E_NUM; ++e) mx = fmaxf(mx, acc[e]);
    float s[E_NUM]; float sum = 0.f;
#pragma unroll
    for (int e = 0; e < E_NUM; ++e) { s[e] = __expf(acc[e] - mx); sum += s[e]; }
    float inv = 1.f / sum;
#pragma unroll
    for (int e = 0; e < E_NUM; ++e) s[e] *= inv;
    int i0 = 0; float w0 = s[0];
#pragma unroll
    for (int e = 1; e < E_NUM; ++e) if (s[e] > w0) { w0 = s[e]; i0 = e; }
    s[i0] = -1.f;
    int i1 = 0; float w1 = s[0];
#pragma unroll
    for (int e = 1; e < E_NUM; ++e) if (s[e] > w1) { w1 = s[e]; i1 = e; }
    expert_idx[2 * t] = i0; expert_idx[2 * t + 1] = i1;
    expert_w[2 * t] = w0;  expert_w[2 * t + 1] = w1;
    atomicAdd(&counts[i0], 1);
    atomicAdd(&counts[i1], 1);
  }
}

// ---------------- plan: offsets + ragged tile metadata + counts output ----------------
__global__ void plan_kernel(const int* __restrict__ counts, int* __restrict__ offsets,
                            int* __restrict__ tile_meta, int* __restrict__ ntilesp,
                            float* __restrict__ out_counts) {
  if (threadIdx.x == 0 && blockIdx.x == 0) {
    int off = 0, nt = 0;
    for (int e = 0; e < E_NUM; ++e) {
      int cnt = counts[e];
      offsets[e] = off;
      out_counts[e] = (float)cnt;
      int ntile = (cnt + 127) >> 7;
      for (int i = 0; i < ntile; ++i) {
        tile_meta[nt * 4 + 0] = off + i * 128;
        tile_meta[nt * 4 + 1] = (cnt - i * 128) < 128 ? (cnt - i * 128) : 128;
        tile_meta[nt * 4 + 2] = e;
        ++nt;
      }
      off += cnt;
    }
    *ntilesp = nt;
  }
}

// ---------------- assign: slot per (token,k) ----------------
__global__ __launch_bounds__(256) void assign_kernel(
    const int* __restrict__ expert_idx, const int* __restrict__ offsets,
    int* __restrict__ cursor, int* __restrict__ row_token, int* __restrict__ slot_of) {
  int i = blockIdx.x * 256 + threadIdx.x;   // [0, NROWS)
  int e = expert_idx[i];
  int pos = atomicAdd(&cursor[e], 1);
  int slot = offsets[e] + pos;
  row_token[slot] = i >> 1;
  slot_of[i] = slot;
}

// ---------------- gather + cast to bf16 ----------------
__global__ __launch_bounds__(256) void gather_kernel(
    const float* __restrict__ x, const int* __restrict__ row_token,
    uint16_t* __restrict__ xs) {
  int row = blockIdx.x;
  int tok = row_token[row];
  int c = threadIdx.x * 8;
  const float4* p = (const float4*)(x + (size_t)tok * H_DIM + c);
  float4 v0 = p[0], v1 = p[1];
  uint32_t p0 = (uint32_t)f2bf(v0.x) | ((uint32_t)f2bf(v0.y) << 16);
  uint32_t p1 = (uint32_t)f2bf(v0.z) | ((uint32_t)f2bf(v0.w) << 16);
  uint32_t p2 = (uint32_t)f2bf(v1.x) | ((uint32_t)f2bf(v1.y) << 16);
  uint32_t p3 = (uint32_t)f2bf(v1.z) | ((uint32_t)f2bf(v1.w) << 16);
  uint4 o; o.x = p0; o.y = p1; o.z = p2; o.w = p3;
  *(uint4*)(xs + (size_t)row * H_DIM + c) = o;
}

// ---------------- transpose+cast: [E][R][C] fp32 -> [E][C][R] bf16 ----------------
__global__ __launch_bounds__(256) void transpose_cast(
    const float* __restrict__ in, uint16_t* __restrict__ out, int R, int C) {
  __shared__ float tile[32][33];
  int e = blockIdx.z;
  int c0 = blockIdx.x * 32, r0 = blockIdx.y * 32;
  const float* src = in + (size_t)e * R * C;
  uint16_t* dst = out + (size_t)e * R * C;
  int tx = threadIdx.x, ty = threadIdx.y;
#pragma unroll
  for (int it = 0; it < 4; ++it) {
    int r = ty + it * 8;
    tile[r][tx] = src[(size_t)(r0 + r) * C + c0 + tx];
  }
  __syncthreads();
#pragma unroll
  for (int it = 0; it < 4; ++it) {
    int c = ty + it * 8;
    dst[(size_t)(c0 + c) * R + r0 + tx] = f2bf(tile[tx][c]);
  }
}

// ---------------- async 16B global->LDS ----------------
__device__ __forceinline__ void gld16(const uint16_t* g, uint16_t* l) {
  __builtin_amdgcn_global_load_lds(
      (const __attribute__((address_space(1))) uint32_t*)(g),
      (__attribute__((address_space(3))) uint32_t*)(l), 16, 0, 0);
}

// ---------------- grouped GEMM: C[rows][N] = A[rows][K] @ Bt[e][N][K]^T ----------------
template <int N, int K, int KITERS, bool GELU>
__global__ __launch_bounds__(256) void gemm_kernel(
    const uint16_t* __restrict__ A, const uint16_t* __restrict__ Bt,
    uint16_t* __restrict__ C,
    const int* __restrict__ tile_meta, const int* __restrict__ ntilesp) {
  int slot = blockIdx.y;
  if (slot >= *ntilesp) return;
  int row_start = tile_meta[slot * 4 + 0];
  int rows = tile_meta[slot * 4 + 1];
  int e = tile_meta[slot * 4 + 2];
  int n0 = blockIdx.x * 128;

  __shared__ uint16_t As[128 * 32];
  __shared__ uint16_t Bs[128 * 32];

  int tid = threadIdx.x;
  int lane = tid & 63;
  int wave = tid >> 6;
  int wm = (wave & 1) * 64;
  int wn = (wave >> 1) * 64;
  int lm = lane & 15;
  int lq = lane >> 4;

  f32x4 acc[4][4];
#pragma unroll
  for (int i = 0; i < 4; ++i)
#pragma unroll
    for (int j = 0; j < 4; ++j) acc[i][j] = (f32x4){0.f, 0.f, 0.f, 0.f};

  // staging: A tile 128 rows x 32 bf16 = 512 chunks of 16B; 256 threads x 2 passes
  int c0i = tid, c1i = tid + 256;
  int rowA0 = c0i >> 2, segA0 = c0i & 3;
  int rowA1 = c1i >> 2, segA1 = c1i & 3;
  int ra0 = rowA0 < rows ? rowA0 : rows - 1;
  int ra1 = rowA1 < rows ? rowA1 : rows - 1;
  const uint16_t* gA0 = A + (size_t)(row_start + ra0) * K + segA0 * 8;
  const uint16_t* gA1 = A + (size_t)(row_start + ra1) * K + segA1 * 8;
  const uint16_t* gB0 = Bt + ((size_t)e * N + n0 + rowA0) * K + segA0 * 8;
  const uint16_t* gB1 = Bt + ((size_t)e * N + n0 + rowA1) * K + segA1 * 8;
  uint16_t* lA0 = As + c0i * 8;
  uint16_t* lA1 = As + c1i * 8;
  uint16_t* lB0 = Bs + c0i * 8;
  uint16_t* lB1 = Bs + c1i * 8;

  for (int kk = 0; kk < KITERS; ++kk) {
    gld16(gA0, lA0);
    gld16(gB0, lB0);
    gld16(gA1, lA1);
    gld16(gB1, lB1);
    gA0 += 32; gA1 += 32; gB0 += 32; gB1 += 32;
    __syncthreads();
    bf16x8 af[4], bfr[4];
#pragma unroll
    for (int mi = 0; mi < 4; ++mi)
      af[mi] = *(const bf16x8*)(As + (wm + mi * 16 + lm) * 32 + lq * 8);
#pragma unroll
    for (int ni = 0; ni < 4; ++ni)
      bfr[ni] = *(const bf16x8*)(Bs + (wn + ni * 16 + lm) * 32 + lq * 8);
#pragma unroll
    for (int mi = 0; mi < 4; ++mi)
#pragma unroll
      for (int ni = 0; ni < 4; ++ni)
        acc[mi][ni] = __builtin_amdgcn_mfma_f32_16x16x32_bf16(af[mi], bfr[ni], acc[mi][ni], 0, 0, 0);
    __syncthreads();
  }

  // epilogue: C/D layout col=lane&15, row=(lane>>4)*4+reg
#pragma unroll
  for (int mi = 0; mi < 4; ++mi) {
#pragma unroll
    for (int r = 0; r < 4; ++r) {
      int lrow = wm + mi * 16 + lq * 4 + r;
      if (lrow < rows) {
        size_t base = (size_t)(row_start + lrow) * N + n0 + wn;
#pragma unroll
        for (int ni = 0; ni < 4; ++ni) {
          float v = acc[mi][ni][r];
          if (GELU) v = gelu_tanh(v);
          C[base + ni * 16 + lm] = f2bf(v);
        }
      }
    }
  }
}

// ---------------- combine: y[t] = w0*out[slot0] + w1*out[slot1] ----------------
__global__ __launch_bounds__(256) void combine_kernel(
    const uint16_t* __restrict__ outb, const int* __restrict__ slot_of,
    const float* __restrict__ ew, float* __restrict__ y) {
  int t = blockIdx.x;
  int s0 = slot_of[2 * t], s1 = slot_of[2 * t + 1];
  float w0 = ew[2 * t], w1 = ew[2 * t + 1];
  int c = threadIdx.x * 8;
  uint4 a = *(const uint4*)(outb + (size_t)s0 * H_DIM + c);
  uint4 b = *(const uint4*)(outb + (size_t)s1 * H_DIM + c);
  float* yp = y + (size_t)t * H_DIM + c;
  float4 r0, r1;
  r0.x = w0 * bf2f(a.x & 0xffffu) + w1 * bf2f(b.x & 0xffffu);
  r0.y = w0 * bf2f(a.x >> 16)     + w1 * bf2f(b.x >> 16);
  r0.z = w0 * bf2f(a.y & 0xffffu) + w1 * bf2f(b.y & 0xffffu);
  r0.w = w0 * bf2f(a.y >> 16)     + w1 * bf2f(b.y >> 16);
  r1.x = w0 * bf2f(a.z & 0xffffu) + w1 * bf2f(b.z & 0xffffu);
  r1.y = w0 * bf2f(a.z >> 16)     + w1 * bf2f(b.z >> 16);
  r1.z = w0 * bf2f(a.w & 0xffffu) + w1 * bf2f(b.w & 0xffffu);
  r1.w = w0 * bf2f(a.w >> 16)     + w1 * bf2f(b.w >> 16);
  *(float4*)yp = r0;
  *(float4*)(yp + 4) = r1;
}

extern "C" void kernel_launch(void* const* d_in, const int* in_sizes, int n_in,
                              void* d_out, int out_size, void* d_ws, size_t ws_size,
                              hipStream_t stream) {
  const float* x  = (const float*)d_in[0];
  const float* rw = (const float*)d_in[1];
  const float* w1 = (const float*)d_in[2];
  const float* w2 = (const float*)d_in[3];
  float* y = (float*)d_out;
  float* out_counts = y + (size_t)T_TOK * H_DIM;   // 8 floats at the tail

  char* ws = (char*)d_ws;
  int* counts     = (int*)(ws + 0);
  int* cursor     = (int*)(ws + 64);
  int* ntilesp    = (int*)(ws + 128);
  int* offsets    = (int*)(ws + 192);
  int* tile_meta  = (int*)(ws + 1024);            // up to 144 tiles * 4 ints
  int* expert_idx = (int*)(ws + 8192);
  float* expert_w = (float*)(ws + 8192 + 65536);
  int* row_token  = (int*)(ws + 8192 + 2 * 65536);
  int* slot_of    = (int*)(ws + 8192 + 3 * 65536);
  const size_t MB = 1ull << 20;
  uint16_t* xs   = (uint16_t*)(ws + 1 * MB);      //  64 MB [NROWS][H]
  uint16_t* hbuf = (uint16_t*)(ws + 66 * MB);     // 128 MB [NROWS][I]
  uint16_t* outb = (uint16_t*)(ws + 194 * MB);    //  64 MB [NROWS][H]
  uint16_t* w1t  = (uint16_t*)(ws + 258 * MB);    // 128 MB [E][I][H]
  uint16_t* w2t  = (uint16_t*)(ws + 386 * MB);    // 128 MB [E][H][I]

  hipMemsetAsync(d_ws, 0, 8192, stream);   // counters/cursors/meta zero

  router_kernel<<<T_TOK / 4, 256, 0, stream>>>(x, rw, expert_idx, expert_w, counts);
  plan_kernel<<<1, 64, 0, stream>>>(counts, offsets, tile_meta, ntilesp, out_counts);
  assign_kernel<<<NROWS / 256, 256, 0, stream>>>(expert_idx, offsets, cursor, row_token, slot_of);
  gather_kernel<<<NROWS, 256, 0, stream>>>(x, row_token, xs);
  transpose_cast<<<dim3(I_DIM / 32, H_DIM / 32, E_NUM), dim3(32, 8), 0, stream>>>(w1, w1t, H_DIM, I_DIM);
  transpose_cast<<<dim3(H_DIM / 32, I_DIM / 32, E_NUM), dim3(32, 8), 0, stream>>>(w2, w2t, I_DIM, H_DIM);
  gemm_kernel<I_DIM, H_DIM, H_DIM / 32, true>
      <<<dim3(I_DIM / 128, 144), 256, 0, stream>>>(xs, w1t, hbuf, tile_meta, ntilesp);
  gemm_kernel<H_DIM, I_DIM, I_DIM / 32, false>
      <<<dim3(H_DIM / 128, 144), 256, 0, stream>>>(hbuf, w2t, outb, tile_meta, ntilesp);
  combine_kernel<<<T_TOK, 256, 0, stream>>>(outb, slot_of, expert_w, y);
}

// Round 2
// 1621.152 us; speedup vs baseline: 1.0253x; 1.0253x over previous
//
#include <hip/hip_runtime.h>
#include <cstdint>
#include <cmath>

// Problem constants (B=4, S=2048, H=2048, I=4096, E=8, K=2)
#define T_TOK 8192     // B*S
#define H_DIM 2048
#define I_DIM 4096
#define E_NUM 8
#define NROWS 16384    // T*K

typedef __bf16 bf16x8 __attribute__((ext_vector_type(8)));
typedef float f32x4 __attribute__((ext_vector_type(4)));

__device__ __forceinline__ uint16_t f2bf(float f) {
  union { float f; uint32_t u; } v; v.f = f;
  uint32_t u = v.u;
  uint32_t r = (u + 0x7fffu + ((u >> 16) & 1u)) >> 16;
  return (uint16_t)r;
}
__device__ __forceinline__ float bf2f(uint32_t b) {
  union { uint32_t u; float f; } v; v.u = b << 16;
  return v.f;
}

__device__ __forceinline__ float gelu_tanh(float x) {
  float u = 0.7978845608028654f * (x + 0.044715f * x * x * x);
  return 0.5f * x * (1.0f + tanhf(u));
}

// ---------------- router: logits -> softmax -> top-2, histogram ----------------
__global__ __launch_bounds__(256) void router_kernel(
    const float* __restrict__ x, const float* __restrict__ rw,
    int* __restrict__ expert_idx, float* __restrict__ expert_w,
    int* __restrict__ counts) {
  int t = blockIdx.x * 4 + (threadIdx.x >> 6);   // one wave per token
  int lane = threadIdx.x & 63;
  const float* xr = x + (size_t)t * H_DIM;
  float acc[E_NUM];
#pragma unroll
  for (int e = 0; e < E_NUM; ++e) acc[e] = 0.f;
  for (int j = 0; j < H_DIM / 64; ++j) {
    float xv = xr[lane + 64 * j];
#pragma unroll
    for (int e = 0; e < E_NUM; ++e) acc[e] += xv * rw[e * H_DIM + lane + 64 * j];
  }
#pragma unroll
  for (int e = 0; e < E_NUM; ++e) {
#pragma unroll
    for (int off = 32; off > 0; off >>= 1) acc[e] += __shfl_xor(acc[e], off);
  }
  if (lane == 0) {
    float mx = acc[0];
#pragma unroll
    for (int e = 1; e < E_NUM; ++e) mx = fmaxf(mx, acc[e]);
    float s[E_NUM]; float sum = 0.f;
#pragma unroll
    for (int e = 0; e < E_NUM; ++e) { s[e] = __expf(acc[e] - mx); sum += s[e]; }
    float inv = 1.f / sum;
#pragma unroll
    for (int e = 0; e < E_NUM; ++e) s[e] *= inv;
    int i0 = 0; float w0 = s[0];
#pragma unroll
    for (int e = 1; e < E_NUM; ++e) if (s[e] > w0) { w0 = s[e]; i0 = e; }
    s[i0] = -1.f;
    int i1 = 0; float w1 = s[0];
#pragma unroll
    for (int e = 1; e < E_NUM; ++e) if (s[e] > w1) { w1 = s[e]; i1 = e; }
    expert_idx[2 * t] = i0; expert_idx[2 * t + 1] = i1;
    expert_w[2 * t] = w0;  expert_w[2 * t + 1] = w1;
    atomicAdd(&counts[i0], 1);
    atomicAdd(&counts[i1], 1);
  }
}

// ---------------- plan: offsets + ragged tile metadata + counts output ----------------
__global__ void plan_kernel(const int* __restrict__ counts, int* __restrict__ offsets,
                            int* __restrict__ tile_meta, int* __restrict__ ntilesp,
                            float* __restrict__ out_counts) {
  if (threadIdx.x == 0 && blockIdx.x == 0) {
    int off = 0, nt = 0;
    for (int e = 0; e < E_NUM; ++e) {
      int cnt = counts[e];
      offsets[e] = off;
      out_counts[e] = (float)cnt;
      int ntile = (cnt + 127) >> 7;
      for (int i = 0; i < ntile; ++i) {
        tile_meta[nt * 4 + 0] = off + i * 128;
        tile_meta[nt * 4 + 1] = (cnt - i * 128) < 128 ? (cnt - i * 128) : 128;
        tile_meta[nt * 4 + 2] = e;
        ++nt;
      }
      off += cnt;
    }
    *ntilesp = nt;
  }
}

// ---------------- assign: slot per (token,k) ----------------
__global__ __launch_bounds__(256) void assign_kernel(
    const int* __restrict__ expert_idx, const int* __restrict__ offsets,
    int* __restrict__ cursor, int* __restrict__ row_token, int* __restrict__ slot_of) {
  int i = blockIdx.x * 256 + threadIdx.x;   // [0, NROWS)
  int e = expert_idx[i];
  int pos = atomicAdd(&cursor[e], 1);
  int slot = offsets[e] + pos;
  row_token[slot] = i >> 1;
  slot_of[i] = slot;
}

// ---------------- gather + cast to bf16 ----------------
__global__ __launch_bounds__(256) void gather_kernel(
    const float* __restrict__ x, const int* __restrict__ row_token,
    uint16_t* __restrict__ xs) {
  int row = blockIdx.x;
  int tok = row_token[row];
  int c = threadIdx.x * 8;
  const float4* p = (const float4*)(x + (size_t)tok * H_DIM + c);
  float4 v0 = p[0], v1 = p[1];
  uint32_t p0 = (uint32_t)f2bf(v0.x) | ((uint32_t)f2bf(v0.y) << 16);
  uint32_t p1 = (uint32_t)f2bf(v0.z) | ((uint32_t)f2bf(v0.w) << 16);
  uint32_t p2 = (uint32_t)f2bf(v1.x) | ((uint32_t)f2bf(v1.y) << 16);
  uint32_t p3 = (uint32_t)f2bf(v1.z) | ((uint32_t)f2bf(v1.w) << 16);
  uint4 o; o.x = p0; o.y = p1; o.z = p2; o.w = p3;
  *(uint4*)(xs + (size_t)row * H_DIM + c) = o;
}

// ---------------- transpose+cast: [E][R][C] fp32 -> [E][C][R] bf16 ----------------
// 64-row x 32-col tile; writes paired bf16 (uint32) -> 128B per 32 lanes.
__global__ __launch_bounds__(256) void transpose_cast(
    const float* __restrict__ in, uint16_t* __restrict__ out, int R, int C) {
  __shared__ float tile[64][33];
  int e = blockIdx.z;
  int c0 = blockIdx.x * 32, r0 = blockIdx.y * 64;
  const float* src = in + (size_t)e * R * C;
  uint16_t* dst = out + (size_t)e * R * C;
  int tx = threadIdx.x, ty = threadIdx.y;   // (32, 8)
#pragma unroll
  for (int it = 0; it < 8; ++it) {
    int r = ty + it * 8;
    tile[r][tx] = src[(size_t)(r0 + r) * C + c0 + tx];
  }
  __syncthreads();
#pragma unroll
  for (int it = 0; it < 4; ++it) {
    int c = ty + it * 8;
    uint32_t lo = f2bf(tile[2 * tx][c]);
    uint32_t hi = f2bf(tile[2 * tx + 1][c]);
    *(uint32_t*)(dst + (size_t)(c0 + c) * R + r0 + 2 * tx) = lo | (hi << 16);
  }
}

// ---------------- async 16B global->LDS ----------------
__device__ __forceinline__ void gld16(const uint16_t* g, uint16_t* l) {
  __builtin_amdgcn_global_load_lds(
      (const __attribute__((address_space(1))) uint32_t*)(g),
      (__attribute__((address_space(3))) uint32_t*)(l), 16, 0, 0);
}

// ---------------- grouped GEMM: C[rows][N] = A[rows][K] @ Bt[e][N][K]^T ----------------
// LDS layout XOR-swizzled: chunk (row, seg_phys) holds global seg_log =
// seg_phys ^ ((row>>1)&3). Fragment readers apply the same XOR -> bank-group
// sequence (4r + swz)%8 covers all 8 groups per 8 rows => 2-way max (free).
template <int N, int K, int KITERS, bool GELU>
__global__ __launch_bounds__(256) void gemm_kernel(
    const uint16_t* __restrict__ A, const uint16_t* __restrict__ Bt,
    uint16_t* __restrict__ C,
    const int* __restrict__ tile_meta, const int* __restrict__ ntilesp) {
  int slot = blockIdx.y;
  if (slot >= *ntilesp) return;
  int row_start = tile_meta[slot * 4 + 0];
  int rows = tile_meta[slot * 4 + 1];
  int e = tile_meta[slot * 4 + 2];
  int n0 = blockIdx.x * 128;

  __shared__ uint16_t As[128 * 32];
  __shared__ uint16_t Bs[128 * 32];

  int tid = threadIdx.x;
  int lane = tid & 63;
  int wave = tid >> 6;
  int wm = (wave & 1) * 64;
  int wn = (wave >> 1) * 64;
  int lm = lane & 15;
  int lq = lane >> 4;

  f32x4 acc[4][4];
#pragma unroll
  for (int i = 0; i < 4; ++i)
#pragma unroll
    for (int j = 0; j < 4; ++j) acc[i][j] = (f32x4){0.f, 0.f, 0.f, 0.f};

  // staging: 512 chunks of 16B per tile; 256 threads x 2 passes.
  // chunk c: row=c>>2, seg_phys=c&3, global seg_log = seg_phys ^ ((row>>1)&3)
  int c0i = tid, c1i = tid + 256;
  int rowA0 = c0i >> 2, segP0 = c0i & 3;
  int rowA1 = c1i >> 2, segP1 = c1i & 3;
  int segL0 = segP0 ^ ((rowA0 >> 1) & 3);
  int segL1 = segP1 ^ ((rowA1 >> 1) & 3);
  int ra0 = rowA0 < rows ? rowA0 : rows - 1;
  int ra1 = rowA1 < rows ? rowA1 : rows - 1;
  const uint16_t* gA0 = A + (size_t)(row_start + ra0) * K + segL0 * 8;
  const uint16_t* gA1 = A + (size_t)(row_start + ra1) * K + segL1 * 8;
  const uint16_t* gB0 = Bt + ((size_t)e * N + n0 + rowA0) * K + segL0 * 8;
  const uint16_t* gB1 = Bt + ((size_t)e * N + n0 + rowA1) * K + segL1 * 8;
  uint16_t* lA0 = As + c0i * 8;
  uint16_t* lA1 = As + c1i * 8;
  uint16_t* lB0 = Bs + c0i * 8;
  uint16_t* lB1 = Bs + c1i * 8;

  for (int kk = 0; kk < KITERS; ++kk) {
    gld16(gA0, lA0);
    gld16(gB0, lB0);
    gld16(gA1, lA1);
    gld16(gB1, lB1);
    gA0 += 32; gA1 += 32; gB0 += 32; gB1 += 32;
    __syncthreads();
    bf16x8 af[4], bfr[4];
#pragma unroll
    for (int mi = 0; mi < 4; ++mi) {
      int r = wm + mi * 16 + lm;
      af[mi] = *(const bf16x8*)(As + r * 32 + (lq ^ ((r >> 1) & 3)) * 8);
    }
#pragma unroll
    for (int ni = 0; ni < 4; ++ni) {
      int r = wn + ni * 16 + lm;
      bfr[ni] = *(const bf16x8*)(Bs + r * 32 + (lq ^ ((r >> 1) & 3)) * 8);
    }
#pragma unroll
    for (int mi = 0; mi < 4; ++mi)
#pragma unroll
      for (int ni = 0; ni < 4; ++ni)
        acc[mi][ni] = __builtin_amdgcn_mfma_f32_16x16x32_bf16(af[mi], bfr[ni], acc[mi][ni], 0, 0, 0);
    __syncthreads();
  }

  // epilogue: C/D layout col=lane&15, row=(lane>>4)*4+reg
#pragma unroll
  for (int mi = 0; mi < 4; ++mi) {
#pragma unroll
    for (int r = 0; r < 4; ++r) {
      int lrow = wm + mi * 16 + lq * 4 + r;
      if (lrow < rows) {
        size_t base = (size_t)(row_start + lrow) * N + n0 + wn;
#pragma unroll
        for (int ni = 0; ni < 4; ++ni) {
          float v = acc[mi][ni][r];
          if (GELU) v = gelu_tanh(v);
          C[base + ni * 16 + lm] = f2bf(v);
        }
      }
    }
  }
}

// ---------------- combine: y[t] = w0*out[slot0] + w1*out[slot1] ----------------
__global__ __launch_bounds__(256) void combine_kernel(
    const uint16_t* __restrict__ outb, const int* __restrict__ slot_of,
    const float* __restrict__ ew, float* __restrict__ y) {
  int t = blockIdx.x;
  int s0 = slot_of[2 * t], s1 = slot_of[2 * t + 1];
  float w0 = ew[2 * t], w1 = ew[2 * t + 1];
  int c = threadIdx.x * 8;
  uint4 a = *(const uint4*)(outb + (size_t)s0 * H_DIM + c);
  uint4 b = *(const uint4*)(outb + (size_t)s1 * H_DIM + c);
  float* yp = y + (size_t)t * H_DIM + c;
  float4 r0, r1;
  r0.x = w0 * bf2f(a.x & 0xffffu) + w1 * bf2f(b.x & 0xffffu);
  r0.y = w0 * bf2f(a.x >> 16)     + w1 * bf2f(b.x >> 16);
  r0.z = w0 * bf2f(a.y & 0xffffu) + w1 * bf2f(b.y & 0xffffu);
  r0.w = w0 * bf2f(a.y >> 16)     + w1 * bf2f(b.y >> 16);
  r1.x = w0 * bf2f(a.z & 0xffffu) + w1 * bf2f(b.z & 0xffffu);
  r1.y = w0 * bf2f(a.z >> 16)     + w1 * bf2f(b.z >> 16);
  r1.z = w0 * bf2f(a.w & 0xffffu) + w1 * bf2f(b.w & 0xffffu);
  r1.w = w0 * bf2f(a.w >> 16)     + w1 * bf2f(b.w >> 16);
  *(float4*)yp = r0;
  *(float4*)(yp + 4) = r1;
}

extern "C" void kernel_launch(void* const* d_in, const int* in_sizes, int n_in,
                              void* d_out, int out_size, void* d_ws, size_t ws_size,
                              hipStream_t stream) {
  const float* x  = (const float*)d_in[0];
  const float* rw = (const float*)d_in[1];
  const float* w1 = (const float*)d_in[2];
  const float* w2 = (const float*)d_in[3];
  float* y = (float*)d_out;
  float* out_counts = y + (size_t)T_TOK * H_DIM;   // 8 floats at the tail

  char* ws = (char*)d_ws;
  int* counts     = (int*)(ws + 0);
  int* cursor     = (int*)(ws + 64);
  int* ntilesp    = (int*)(ws + 128);
  int* offsets    = (int*)(ws + 192);
  int* tile_meta  = (int*)(ws + 1024);            // up to 144 tiles * 4 ints
  int* expert_idx = (int*)(ws + 8192);
  float* expert_w = (float*)(ws + 8192 + 65536);
  int* row_token  = (int*)(ws + 8192 + 2 * 65536);
  int* slot_of    = (int*)(ws + 8192 + 3 * 65536);
  const size_t MB = 1ull << 20;
  uint16_t* xs   = (uint16_t*)(ws + 1 * MB);      //  64 MB [NROWS][H]
  uint16_t* hbuf = (uint16_t*)(ws + 66 * MB);     // 128 MB [NROWS][I]
  uint16_t* outb = (uint16_t*)(ws + 194 * MB);    //  64 MB [NROWS][H]
  uint16_t* w1t  = (uint16_t*)(ws + 258 * MB);    // 128 MB [E][I][H]
  uint16_t* w2t  = (uint16_t*)(ws + 386 * MB);    // 128 MB [E][H][I]

  hipMemsetAsync(d_ws, 0, 8192, stream);   // counters/cursors/meta zero

  router_kernel<<<T_TOK / 4, 256, 0, stream>>>(x, rw, expert_idx, expert_w, counts);
  plan_kernel<<<1, 64, 0, stream>>>(counts, offsets, tile_meta, ntilesp, out_counts);
  assign_kernel<<<NROWS / 256, 256, 0, stream>>>(expert_idx, offsets, cursor, row_token, slot_of);
  gather_kernel<<<NROWS, 256, 0, stream>>>(x, row_token, xs);
  transpose_cast<<<dim3(I_DIM / 32, H_DIM / 64, E_NUM), dim3(32, 8), 0, stream>>>(w1, w1t, H_DIM, I_DIM);
  transpose_cast<<<dim3(H_DIM / 32, I_DIM / 64, E_NUM), dim3(32, 8), 0, stream>>>(w2, w2t, I_DIM, H_DIM);
  gemm_kernel<I_DIM, H_DIM, H_DIM / 32, true>
      <<<dim3(I_DIM / 128, 144), 256, 0, stream>>>(xs, w1t, hbuf, tile_meta, ntilesp);
  gemm_kernel<H_DIM, I_DIM, I_DIM / 32, false>
      <<<dim3(H_DIM / 128, 144), 256, 0, stream>>>(hbuf, w2t, outb, tile_meta, ntilesp);
  combine_kernel<<<T_TOK, 256, 0, stream>>>(outb, slot_of, expert_w, y);
}